// Round 1
// baseline (562.029 us; speedup 1.0000x reference)
//
#include <hip/hip_runtime.h>
#include <hip/hip_bf16.h>
#include <stdint.h>

// Problem constants (TernaryLinear: x[8192,4096] fp32 @ W[4096,4096]^T + b)
#define M_DIM 8192
#define N_DIM 4096
#define K_DIM 4096
#define BM 128
#define BN 128
#define BK 32

typedef float floatx4 __attribute__((ext_vector_type(4)));
typedef __bf16 bf16x8 __attribute__((ext_vector_type(8)));

typedef __attribute__((address_space(1))) void gv_t;
typedef __attribute__((address_space(3))) void lv_t;

// async global->LDS, 16B per lane. LDS dest is wave-uniform base + lane*16.
__device__ __forceinline__ void gl2lds16(const void* g, void* l) {
    __builtin_amdgcn_global_load_lds((const gv_t*)g, (lv_t*)l, 16, 0, 0);
}

__device__ __forceinline__ unsigned short f2bf_rne(float f) {
    uint32_t u = __float_as_uint(f);
    u += 0x7FFFu + ((u >> 16) & 1u);   // round-to-nearest-even
    return (unsigned short)(u >> 16);
}

// fp32 -> bf16, 8 elements per thread (two float4 loads, one 16B store)
__global__ __launch_bounds__(256) void cvt_f32_to_bf16_x8(
    const float* __restrict__ in, unsigned short* __restrict__ out, int n8) {
    int i = blockIdx.x * 256 + threadIdx.x;
    if (i >= n8) return;
    const float4* p = (const float4*)in + (size_t)i * 2;
    float4 a = p[0];
    float4 b = p[1];
    union { unsigned short u[8]; uint4 v; } r;
    r.u[0] = f2bf_rne(a.x); r.u[1] = f2bf_rne(a.y);
    r.u[2] = f2bf_rne(a.z); r.u[3] = f2bf_rne(a.w);
    r.u[4] = f2bf_rne(b.x); r.u[5] = f2bf_rne(b.y);
    r.u[6] = f2bf_rne(b.z); r.u[7] = f2bf_rne(b.w);
    *((uint4*)out + i) = r.v;
}

// m97-structure bf16 GEMM, B^T input: C[m,n] = sum_k A[m,k]*B[n,k] + bias[n]
// 128x128 tile, BK=32, 4 waves (2x2), each wave 64x64 via 4x4 mfma 16x16x32.
__global__ __launch_bounds__(256, 3) void gemm_bt_bf16(
    const unsigned short* __restrict__ A,   // M x K, bf16 bits
    const unsigned short* __restrict__ B,   // N x K, bf16 bits
    const float* __restrict__ bias,         // N
    float* __restrict__ C) {                // M x N fp32
    __shared__ unsigned short sA[BM * BK];  // 8 KiB
    __shared__ unsigned short sB[BN * BK];  // 8 KiB

    const int tid  = threadIdx.x;
    const int lane = tid & 63;
    const int wv   = tid >> 6;     // 0..3
    const int wm   = wv >> 1;      // wave row (0..1)
    const int wn   = wv & 1;       // wave col (0..1)

    const int row0 = blockIdx.y * BM;
    const int col0 = blockIdx.x * BN;

    // --- staging layout: 4 lanes per 64B row-chunk, 16 rows/wave/pass ---
    const int srow  = wv * 16 + (lane >> 2);   // 0..63 (pass covers 64 rows)
    const int skofs = (lane & 3) * 8;          // bf16-element offset in k

    const unsigned short* gA = A + (size_t)(row0 + srow) * K_DIM + skofs;
    const unsigned short* gB = B + (size_t)(col0 + srow) * K_DIM + skofs;
    const size_t stride64 = (size_t)64 * K_DIM;

    unsigned short* lA0 = &sA[srow * BK + skofs];
    unsigned short* lA1 = &sA[(srow + 64) * BK + skofs];
    unsigned short* lB0 = &sB[srow * BK + skofs];
    unsigned short* lB1 = &sB[(srow + 64) * BK + skofs];

    // --- fragment read coords (A-layout: row=lane&15, k=(lane>>4)*8) ---
    const int fr = lane & 15;
    const int fk = (lane >> 4) * 8;
    const unsigned short* fA = &sA[(wm * 64 + fr) * BK + fk];
    const unsigned short* fB = &sB[(wn * 64 + fr) * BK + fk];

    floatx4 acc[4][4];
#pragma unroll
    for (int i = 0; i < 4; i++)
#pragma unroll
        for (int j = 0; j < 4; j++) acc[i][j] = (floatx4)0.0f;

    for (int k0 = 0; k0 < K_DIM; k0 += BK) {
        __syncthreads();   // previous tile fully consumed
        gl2lds16(gA,            lA0);
        gl2lds16(gA + stride64, lA1);
        gl2lds16(gB,            lB0);
        gl2lds16(gB + stride64, lB1);
        gA += BK; gB += BK;
        __syncthreads();   // drains vmcnt(0) -> staged tile visible

        bf16x8 af[4], bf[4];
#pragma unroll
        for (int i = 0; i < 4; i++) af[i] = *(const bf16x8*)(fA + i * 16 * BK);
#pragma unroll
        for (int j = 0; j < 4; j++) bf[j] = *(const bf16x8*)(fB + j * 16 * BK);
#pragma unroll
        for (int i = 0; i < 4; i++)
#pragma unroll
            for (int j = 0; j < 4; j++)
                acc[i][j] = __builtin_amdgcn_mfma_f32_16x16x32_bf16(
                    af[i], bf[j], acc[i][j], 0, 0, 0);
    }

    // --- epilogue: C/D layout col=lane&15, row=(lane>>4)*4+reg ---
    const int ccol  = lane & 15;
    const int crow4 = (lane >> 4) * 4;
#pragma unroll
    for (int j = 0; j < 4; j++) {
        const int col = col0 + wn * 64 + j * 16 + ccol;
        const float bv = bias[col];
#pragma unroll
        for (int i = 0; i < 4; i++) {
            const int rowb = row0 + wm * 64 + i * 16 + crow4;
            float* cp = C + (size_t)rowb * N_DIM + col;
#pragma unroll
            for (int r = 0; r < 4; r++)
                cp[(size_t)r * N_DIM] = acc[i][j][r] + bv;
        }
    }
}

// Correctness fallback if workspace is too small for bf16 staging.
__global__ __launch_bounds__(256) void naive_ternary(
    const float* __restrict__ x, const float* __restrict__ w,
    const float* __restrict__ bias, float* __restrict__ out) {
    const int col = blockIdx.x * 64 + (threadIdx.x & 63);
    const int row = blockIdx.y * 4 + (threadIdx.x >> 6);
    const float* xr = x + (size_t)row * K_DIM;
    const float* wr = w + (size_t)col * K_DIM;
    float s = 0.f;
    for (int k = 0; k < K_DIM; ++k) s += xr[k] * wr[k];
    out[(size_t)row * N_DIM + col] = s + bias[col];
}

extern "C" void kernel_launch(void* const* d_in, const int* in_sizes, int n_in,
                              void* d_out, int out_size, void* d_ws, size_t ws_size,
                              hipStream_t stream) {
    const float* x    = (const float*)d_in[0];
    const float* w    = (const float*)d_in[1];
    const float* bias = (const float*)d_in[2];
    float* out = (float*)d_out;

    const size_t xN = (size_t)M_DIM * K_DIM;   // 33,554,432
    const size_t wN = (size_t)N_DIM * K_DIM;   // 16,777,216
    const size_t need = (xN + wN) * sizeof(unsigned short);  // ~100.7 MB

    if (ws_size >= need) {
        unsigned short* xb = (unsigned short*)d_ws;
        unsigned short* wb = xb + xN;
        cvt_f32_to_bf16_x8<<<(int)(xN / 8 / 256), 256, 0, stream>>>(x, xb, (int)(xN / 8));
        cvt_f32_to_bf16_x8<<<(int)(wN / 8 / 256), 256, 0, stream>>>(w, wb, (int)(wN / 8));
        dim3 grid(N_DIM / BN, M_DIM / BM);   // (32, 64)
        gemm_bt_bf16<<<grid, 256, 0, stream>>>(xb, wb, bias, out);
    } else {
        dim3 grid(N_DIM / 64, M_DIM / 4);
        naive_ternary<<<grid, 256, 0, stream>>>(x, w, bias, out);
    }
}

// Round 2
// 415.485 us; speedup vs baseline: 1.3527x; 1.3527x over previous
//
#include <hip/hip_runtime.h>
#include <hip/hip_bf16.h>
#include <stdint.h>

// TernaryLinear: C[8192,4096] = x[8192,4096] @ W[4096,4096]^T + b
// i8 path: W is exactly {-1,0,+1} -> int8 exact; x quantized per-row absmax.
#define M_DIM 8192
#define N_DIM 4096
#define K_DIM 4096
#define BM 128
#define BN 128
#define BKI 64   // i8 K-tile: one mfma_i32_16x16x64_i8 K-step per iteration

typedef int intx4 __attribute__((ext_vector_type(4)));

typedef __attribute__((address_space(1))) void gv_t;
typedef __attribute__((address_space(3))) void lv_t;

// async global->LDS, 16B per lane. LDS dest is wave-uniform base + lane*16.
__device__ __forceinline__ void gl2lds16(const void* g, void* l) {
    __builtin_amdgcn_global_load_lds((const gv_t*)g, (lv_t*)l, 16, 0, 0);
}

__device__ __forceinline__ int pack4_scaled(float4 v, float s) {
    int a = __float2int_rn(v.x * s) & 255;
    int b = __float2int_rn(v.y * s) & 255;
    int c = __float2int_rn(v.z * s) & 255;
    int d = __float2int_rn(v.w * s) & 255;
    return a | (b << 8) | (c << 16) | (d << 24);
}

// x fp32 -> i8 with per-row absmax scale. One block per row; 256 thr x 16 elem.
__global__ __launch_bounds__(256) void quant_x_i8(
    const float* __restrict__ x, signed char* __restrict__ q,
    float* __restrict__ dq) {
    const int row = blockIdx.x;
    const int tid = threadIdx.x;
    const float4* p = (const float4*)(x + (size_t)row * K_DIM) + (size_t)tid * 4;
    float4 v0 = p[0], v1 = p[1], v2 = p[2], v3 = p[3];
    float m = fmaxf(fmaxf(fabsf(v0.x), fabsf(v0.y)), fmaxf(fabsf(v0.z), fabsf(v0.w)));
    m = fmaxf(m, fmaxf(fmaxf(fabsf(v1.x), fabsf(v1.y)), fmaxf(fabsf(v1.z), fabsf(v1.w))));
    m = fmaxf(m, fmaxf(fmaxf(fabsf(v2.x), fabsf(v2.y)), fmaxf(fabsf(v2.z), fabsf(v2.w))));
    m = fmaxf(m, fmaxf(fmaxf(fabsf(v3.x), fabsf(v3.y)), fmaxf(fabsf(v3.z), fabsf(v3.w))));
#pragma unroll
    for (int off = 32; off >= 1; off >>= 1)
        m = fmaxf(m, __shfl_xor(m, off, 64));
    __shared__ float wmax[4];
    if ((tid & 63) == 0) wmax[tid >> 6] = m;
    __syncthreads();
    const float rm = fmaxf(fmaxf(wmax[0], wmax[1]), fmaxf(wmax[2], wmax[3]));
    const float s = rm > 0.f ? 127.f / rm : 0.f;
    if (tid == 0) dq[row] = rm * (1.f / 127.f);
    int4 r;
    r.x = pack4_scaled(v0, s);
    r.y = pack4_scaled(v1, s);
    r.z = pack4_scaled(v2, s);
    r.w = pack4_scaled(v3, s);
    *((int4*)(q + (size_t)row * K_DIM) + tid) = r;
}

// W fp32 (exactly -1/0/+1) -> i8. 16 elems per thread.
__global__ __launch_bounds__(256) void quant_w_i8(
    const float* __restrict__ w, signed char* __restrict__ q) {
    const size_t i = (size_t)blockIdx.x * 256 + threadIdx.x;
    const float4* p = (const float4*)w + i * 4;
    float4 v0 = p[0], v1 = p[1], v2 = p[2], v3 = p[3];
    int4 r;
    r.x = pack4_scaled(v0, 1.f);
    r.y = pack4_scaled(v1, 1.f);
    r.z = pack4_scaled(v2, 1.f);
    r.w = pack4_scaled(v3, 1.f);
    ((int4*)q)[i] = r;
}

// m97-structure i8 GEMM, B^T input: C[m,n] = (sum_k Aq[m,k]*Bq[n,k])*dq[m] + bias[n]
// 128x128 tile, BK=64, 4 waves (2x2), each wave 64x64 via 4x4 mfma_i32_16x16x64_i8.
__global__ __launch_bounds__(256, 3) void gemm_bt_i8(
    const signed char* __restrict__ A,   // M x K i8
    const signed char* __restrict__ B,   // N x K i8
    const float* __restrict__ dq,        // M per-row dequant scale
    const float* __restrict__ bias,      // N
    float* __restrict__ C) {             // M x N fp32
    __shared__ signed char sA[BM * BKI]; // 8 KiB
    __shared__ signed char sB[BN * BKI]; // 8 KiB

    const int tid  = threadIdx.x;
    const int lane = tid & 63;
    const int wv   = tid >> 6;
    const int wm   = wv >> 1;
    const int wn   = wv & 1;

    const int row0 = blockIdx.y * BM;
    const int col0 = blockIdx.x * BN;

    // staging: row = 64 bytes = 4 lanes x 16B; one pass covers 64 rows/wave-quad
    const int srow  = wv * 16 + (lane >> 2);
    const int skofs = (lane & 3) * 16;

    const signed char* gA = A + (size_t)(row0 + srow) * K_DIM + skofs;
    const signed char* gB = B + (size_t)(col0 + srow) * K_DIM + skofs;
    const size_t stride64 = (size_t)64 * K_DIM;

    signed char* lA0 = &sA[srow * BKI + skofs];
    signed char* lA1 = &sA[(srow + 64) * BKI + skofs];
    signed char* lB0 = &sB[srow * BKI + skofs];
    signed char* lB1 = &sB[(srow + 64) * BKI + skofs];

    // fragment coords: m/n = lane&15, k-chunk = (lane>>4)*16 bytes
    const int fr = lane & 15;
    const int fk = (lane >> 4) * 16;
    const signed char* fA = &sA[(wm * 64 + fr) * BKI + fk];
    const signed char* fB = &sB[(wn * 64 + fr) * BKI + fk];

    intx4 acc[4][4];
#pragma unroll
    for (int i = 0; i < 4; i++)
#pragma unroll
        for (int j = 0; j < 4; j++) acc[i][j] = (intx4)0;

    for (int k0 = 0; k0 < K_DIM; k0 += BKI) {
        __syncthreads();
        gl2lds16(gA,            lA0);
        gl2lds16(gA + stride64, lA1);
        gl2lds16(gB,            lB0);
        gl2lds16(gB + stride64, lB1);
        gA += BKI; gB += BKI;
        __syncthreads();

        intx4 af[4], bf[4];
#pragma unroll
        for (int i = 0; i < 4; i++) af[i] = *(const intx4*)(fA + i * 16 * BKI);
#pragma unroll
        for (int j = 0; j < 4; j++) bf[j] = *(const intx4*)(fB + j * 16 * BKI);
#pragma unroll
        for (int i = 0; i < 4; i++)
#pragma unroll
            for (int j = 0; j < 4; j++)
                acc[i][j] = __builtin_amdgcn_mfma_i32_16x16x64_i8(
                    af[i], bf[j], acc[i][j], 0, 0, 0);
    }

    // epilogue: C/D layout col=lane&15, row=(lane>>4)*4+reg (dtype-independent)
    const int ccol  = lane & 15;
    const int crow4 = (lane >> 4) * 4;
    const int rbase = row0 + wm * 64 + crow4;
    float rs[4][4];
#pragma unroll
    for (int i = 0; i < 4; i++)
#pragma unroll
        for (int r = 0; r < 4; r++) rs[i][r] = dq[rbase + i * 16 + r];
#pragma unroll
    for (int j = 0; j < 4; j++) {
        const int col = col0 + wn * 64 + j * 16 + ccol;
        const float bv = bias[col];
#pragma unroll
        for (int i = 0; i < 4; i++) {
            float* cp = C + (size_t)(rbase + i * 16) * N_DIM + col;
#pragma unroll
            for (int r = 0; r < 4; r++)
                cp[(size_t)r * N_DIM] = (float)acc[i][j][r] * rs[i][r] + bv;
        }
    }
}

// Correctness fallback if workspace is too small.
__global__ __launch_bounds__(256) void naive_ternary(
    const float* __restrict__ x, const float* __restrict__ w,
    const float* __restrict__ bias, float* __restrict__ out) {
    const int col = blockIdx.x * 64 + (threadIdx.x & 63);
    const int row = blockIdx.y * 4 + (threadIdx.x >> 6);
    const float* xr = x + (size_t)row * K_DIM;
    const float* wr = w + (size_t)col * K_DIM;
    float s = 0.f;
    for (int k = 0; k < K_DIM; ++k) s += xr[k] * wr[k];
    out[(size_t)row * N_DIM + col] = s + bias[col];
}

extern "C" void kernel_launch(void* const* d_in, const int* in_sizes, int n_in,
                              void* d_out, int out_size, void* d_ws, size_t ws_size,
                              hipStream_t stream) {
    const float* x    = (const float*)d_in[0];
    const float* w    = (const float*)d_in[1];
    const float* bias = (const float*)d_in[2];
    float* out = (float*)d_out;

    const size_t xN = (size_t)M_DIM * K_DIM;   // 33.55M
    const size_t wN = (size_t)N_DIM * K_DIM;   // 16.78M
    const size_t need = xN + wN + (size_t)M_DIM * sizeof(float);  // ~50.4 MB

    if (ws_size >= need) {
        signed char* xq = (signed char*)d_ws;
        signed char* wq = xq + xN;
        float* dq = (float*)(wq + wN);
        quant_x_i8<<<M_DIM, 256, 0, stream>>>(x, xq, dq);
        quant_w_i8<<<(int)(wN / 16 / 256), 256, 0, stream>>>(w, wq);
        dim3 grid(N_DIM / BN, M_DIM / BM);   // (32, 64)
        gemm_bt_i8<<<grid, 256, 0, stream>>>(xq, wq, dq, bias, out);
    } else {
        dim3 grid(N_DIM / 64, M_DIM / 4);
        naive_ternary<<<grid, 256, 0, stream>>>(x, w, bias, out);
    }
}